// Round 1
// baseline (4011.259 us; speedup 1.0000x reference)
//
#include <hip/hip_runtime.h>
#include <hip/hip_bf16.h>

#define EPS 1e-6f
typedef unsigned short b16;

__device__ __forceinline__ float b2f(b16 u) {
    return __uint_as_float(((unsigned int)u) << 16);
}
__device__ __forceinline__ b16 f2b(float f) {
    __hip_bfloat16 h = __float2bfloat16(f);
    return *reinterpret_cast<b16*>(&h);
}
__device__ __forceinline__ float bflo(unsigned int u){ return __uint_as_float(u << 16); }
__device__ __forceinline__ float bfhi(unsigned int u){ return __uint_as_float(u & 0xffff0000u); }
__device__ __forceinline__ float siluf(float x) { return x / (1.f + __expf(-x)); }

// ---------------- weight fp32 -> bf16 ----------------
__global__ void __launch_bounds__(256) k_cvt(const float* __restrict__ w, b16* __restrict__ o, int n) {
    int i = blockIdx.x * 256 + threadIdx.x;
    if (i < n) o[i] = f2b(w[i]);
}

// ---------------- A: LN(64)+affine+silu+mask, 2x2x2 masked mean pool ----------------
// one wave per output cell; lane = channel (C=64)
__global__ void __launch_bounds__(256) k_ln_down(
    const float* __restrict__ feats, const int* __restrict__ mask,
    const float* __restrict__ gamma, const float* __restrict__ beta,
    b16* __restrict__ h_ds, b16* __restrict__ x_ds, float* __restrict__ cnt_out)
{
    int wave = (blockIdx.x * 256 + threadIdx.x) >> 6;   // cell id, 0..131071
    int lane = threadIdx.x & 63;
    int x = wave & 31, y = (wave >> 5) & 31, z = (wave >> 10) & 31, b = wave >> 15;
    float g = gamma[lane], be = beta[lane];
    float hacc = 0.f, xacc = 0.f, cnt = 0.f;
    #pragma unroll
    for (int i = 0; i < 8; ++i) {
        int zz = 2*z + (i>>2), yy = 2*y + ((i>>1)&1), xx = 2*x + (i&1);
        int vox = ((b*64 + zz)*64 + yy)*64 + xx;
        int m = mask[vox];        // works for int32 0/1 or float32 0.0/1.0 bit patterns
        float val = feats[vox*64 + lane];
        float s1 = val, s2 = val*val;
        #pragma unroll
        for (int off = 32; off > 0; off >>= 1) {
            s1 += __shfl_xor(s1, off, 64);
            s2 += __shfl_xor(s2, off, 64);
        }
        float mu = s1 * (1.f/64.f);
        float var = fmaxf(s2 * (1.f/64.f) - mu*mu, 0.f);
        float h = (val - mu) * rsqrtf(var + EPS) * g + be;
        h = siluf(h);
        if (m != 0) { hacc += h; xacc += val; cnt += 1.f; }
    }
    float inv = 1.f / fmaxf(cnt, 1.f);
    h_ds[wave*64 + lane] = f2b(hacc * inv);
    x_ds[wave*64 + lane] = f2b(xacc * inv);
    if (lane == 0) cnt_out[wave] = cnt;
}

// ---------------- B: conv1 (64->128) + LN(128) + silu + mask -> h2 (bf16) ----------------
// block: 256 thr = 2 row-groups x 128 oc. Each thread: 8 voxels along W.
__global__ void __launch_bounds__(256) k_conv1(
    const b16* __restrict__ h_ds, const b16* __restrict__ w1b,
    const float* __restrict__ b1, const float* __restrict__ cnt,
    b16* __restrict__ h2)
{
    __shared__ b16 patch[3*4*64*12];   // [zi][yi][c][x(10,pad12)] bf16 = 18432 B
    __shared__ float red[4][2];
    int bid = blockIdx.x;
    int x0 = (bid & 3) << 3;
    int y0 = ((bid >> 2) & 15) << 1;
    int z  = (bid >> 6) & 31;
    int b  = bid >> 11;

    for (int e = threadIdx.x; e < 3*4*10*64; e += 256) {
        int c = e & 63;
        int t = e >> 6;          // 0..119
        int xq = t % 10;
        int yi = (t / 10) & 3;
        int zi = t / 40;
        int zz = z - 1 + zi, yy = y0 - 1 + yi, xx = x0 - 1 + xq;
        b16 v = (b16)0;
        if ((unsigned)zz < 32u && (unsigned)yy < 32u && (unsigned)xx < 32u)
            v = h_ds[(((b*32+zz)*32+yy)*32+xx)*64 + c];
        patch[((zi*4+yi)*64 + c)*12 + xq] = v;
    }
    __syncthreads();

    int rg = threadIdx.x >> 7;   // row group 0/1
    int oc = threadIdx.x & 127;
    float acc[8] = {0.f,0.f,0.f,0.f,0.f,0.f,0.f,0.f};
    for (int kz = 0; kz < 3; ++kz)
    for (int ky = 0; ky < 3; ++ky) {
        const b16* prow = patch + ((kz*4 + rg + ky) * 64) * 12;
        const b16* wrow = w1b + ((kz*3+ky)*3) * 64 * 128 + oc;
        for (int ic = 0; ic < 64; ++ic) {
            const b16* pp = prow + ic*12;
            unsigned int q0 = *reinterpret_cast<const unsigned int*>(pp);
            unsigned int q1 = *reinterpret_cast<const unsigned int*>(pp+2);
            unsigned int q2 = *reinterpret_cast<const unsigned int*>(pp+4);
            unsigned int q3 = *reinterpret_cast<const unsigned int*>(pp+6);
            unsigned int q4 = *reinterpret_cast<const unsigned int*>(pp+8);
            float p[10] = { bflo(q0), bfhi(q0), bflo(q1), bfhi(q1), bflo(q2),
                            bfhi(q2), bflo(q3), bfhi(q3), bflo(q4), bfhi(q4) };
            #pragma unroll
            for (int kx = 0; kx < 3; ++kx) {
                float w = b2f(wrow[(kx*64 + ic)*128]);
                #pragma unroll
                for (int v = 0; v < 8; ++v)
                    acc[v] = fmaf(p[kx+v], w, acc[v]);
            }
        }
    }

    // epilogue: +b1, LN over 128 oc (2 waves), silu, mask, store bf16
    float b1c = b1[oc];
    int yb = y0 + rg;
    int cellBase = ((b*32 + z)*32 + yb)*32 + x0;
    int wid = threadIdx.x >> 6;
    #pragma unroll
    for (int v = 0; v < 8; ++v) {
        int cell = cellBase + v;
        float val = acc[v] + b1c;
        float s1 = val, s2 = val*val;
        #pragma unroll
        for (int off = 32; off > 0; off >>= 1) {
            s1 += __shfl_xor(s1, off, 64);
            s2 += __shfl_xor(s2, off, 64);
        }
        if ((threadIdx.x & 63) == 0) { red[wid][0] = s1; red[wid][1] = s2; }
        __syncthreads();
        float S1 = red[wid][0] + red[wid^1][0];
        float S2 = red[wid][1] + red[wid^1][1];
        __syncthreads();
        float mu = S1 * (1.f/128.f);
        float var = fmaxf(S2 * (1.f/128.f) - mu*mu, 0.f);
        float nv = (val - mu) * rsqrtf(var + EPS);
        bool act = cnt[cell] > 0.f;
        h2[cell*128 + oc] = f2b(act ? siluf(nv) : 0.f);
    }
}

// ---------------- C: conv2 (128->128) + bias + skip (x_ds@w_skip+b_skip) + mask -> out ----------------
__global__ void __launch_bounds__(256) k_conv2(
    const b16* __restrict__ h2, const b16* __restrict__ w2b,
    const float* __restrict__ b2, const b16* __restrict__ x_ds,
    const float* __restrict__ w_skip, const float* __restrict__ b_skip,
    const float* __restrict__ cnt, float* __restrict__ out)
{
    __shared__ b16 patch[3*4*128*12];  // 36864 B
    __shared__ b16 xs[2*8*64];         // 2048 B
    int bid = blockIdx.x;
    int x0 = (bid & 3) << 3;
    int y0 = ((bid >> 2) & 15) << 1;
    int z  = (bid >> 6) & 31;
    int b  = bid >> 11;

    for (int e = threadIdx.x; e < 3*4*10*128; e += 256) {
        int c = e & 127;
        int t = e >> 7;          // 0..119
        int xq = t % 10;
        int yi = (t / 10) & 3;
        int zi = t / 40;
        int zz = z - 1 + zi, yy = y0 - 1 + yi, xx = x0 - 1 + xq;
        b16 v = (b16)0;
        if ((unsigned)zz < 32u && (unsigned)yy < 32u && (unsigned)xx < 32u)
            v = h2[(((b*32+zz)*32+yy)*32+xx)*128 + c];
        patch[((zi*4+yi)*128 + c)*12 + xq] = v;
    }
    for (int e = threadIdx.x; e < 2*8*64; e += 256) {
        int c = e & 63;
        int xi = (e >> 6) & 7;
        int r = e >> 9;
        xs[(r*8 + xi)*64 + c] = x_ds[((((b*32+z)*32 + (y0+r))*32) + x0 + xi)*64 + c];
    }
    __syncthreads();

    int rg = threadIdx.x >> 7;
    int oc = threadIdx.x & 127;
    float acc[8] = {0.f,0.f,0.f,0.f,0.f,0.f,0.f,0.f};
    for (int kz = 0; kz < 3; ++kz)
    for (int ky = 0; ky < 3; ++ky) {
        const b16* prow = patch + ((kz*4 + rg + ky) * 128) * 12;
        const b16* wrow = w2b + ((kz*3+ky)*3) * 128 * 128 + oc;
        for (int ic = 0; ic < 128; ++ic) {
            const b16* pp = prow + ic*12;
            unsigned int q0 = *reinterpret_cast<const unsigned int*>(pp);
            unsigned int q1 = *reinterpret_cast<const unsigned int*>(pp+2);
            unsigned int q2 = *reinterpret_cast<const unsigned int*>(pp+4);
            unsigned int q3 = *reinterpret_cast<const unsigned int*>(pp+6);
            unsigned int q4 = *reinterpret_cast<const unsigned int*>(pp+8);
            float p[10] = { bflo(q0), bfhi(q0), bflo(q1), bfhi(q1), bflo(q2),
                            bfhi(q2), bflo(q3), bfhi(q3), bflo(q4), bfhi(q4) };
            #pragma unroll
            for (int kx = 0; kx < 3; ++kx) {
                float w = b2f(wrow[(kx*128 + ic)*128]);
                #pragma unroll
                for (int v = 0; v < 8; ++v)
                    acc[v] = fmaf(p[kx+v], w, acc[v]);
            }
        }
    }

    // skip: x_ds @ w_skip
    float sacc[8] = {0.f,0.f,0.f,0.f,0.f,0.f,0.f,0.f};
    for (int ic = 0; ic < 64; ++ic) {
        float wv = w_skip[ic*128 + oc];
        #pragma unroll
        for (int v = 0; v < 8; ++v)
            sacc[v] = fmaf(b2f(xs[(rg*8 + v)*64 + ic]), wv, sacc[v]);
    }

    float b2c = b2[oc];
    float bsc = b_skip[oc];
    int yb = y0 + rg;
    int cellBase = ((b*32 + z)*32 + yb)*32 + x0;
    #pragma unroll
    for (int v = 0; v < 8; ++v) {
        int cell = cellBase + v;
        bool act = cnt[cell] > 0.f;
        out[cell*128 + oc] = act ? (acc[v] + b2c + sacc[v] + bsc) : 0.f;
    }
}

extern "C" void kernel_launch(void* const* d_in, const int* in_sizes, int n_in,
                              void* d_out, int out_size, void* d_ws, size_t ws_size,
                              hipStream_t stream) {
    const float* feats  = (const float*)d_in[0];
    const int*   mask   = (const int*)  d_in[1];
    const float* gamma1 = (const float*)d_in[2];
    const float* beta1  = (const float*)d_in[3];
    const float* w1     = (const float*)d_in[4];
    const float* b1     = (const float*)d_in[5];
    const float* w2     = (const float*)d_in[6];
    const float* b2     = (const float*)d_in[7];
    const float* w_skip = (const float*)d_in[8];
    const float* b_skip = (const float*)d_in[9];
    float* out = (float*)d_out;

    char* ws = (char*)d_ws;
    b16*   h_ds = (b16*)(ws);                         // 8,388,608 elems -> 16,777,216 B
    b16*   x_ds = (b16*)(ws + 16777216);              // 16,777,216 B
    b16*   h2   = (b16*)(ws + 33554432);              // 16,777,216 elems -> 33,554,432 B
    float* cnt  = (float*)(ws + 67108864);            // 524,288 B
    b16*   w1b  = (b16*)(ws + 67633152);              // 442,368 B
    b16*   w2b  = (b16*)(ws + 68075520);              // 884,736 B  (total ~69 MB)

    const int n_w1 = 3*3*3*64*128;    // 221184
    const int n_w2 = 3*3*3*128*128;   // 442368
    k_cvt<<<(n_w1 + 255)/256, 256, 0, stream>>>(w1, w1b, n_w1);
    k_cvt<<<(n_w2 + 255)/256, 256, 0, stream>>>(w2, w2b, n_w2);

    k_ln_down<<<32768, 256, 0, stream>>>(feats, mask, gamma1, beta1, h_ds, x_ds, cnt);
    k_conv1<<<8192, 256, 0, stream>>>(h_ds, w1b, b1, cnt, h2);
    k_conv2<<<8192, 256, 0, stream>>>(h2, w2b, b2, x_ds, w_skip, b_skip, cnt, out);
}

// Round 2
// 1186.327 us; speedup vs baseline: 3.3812x; 3.3812x over previous
//
#include <hip/hip_runtime.h>
#include <hip/hip_bf16.h>

#define EPS 1e-6f
typedef unsigned short b16;
typedef __attribute__((ext_vector_type(8))) short v8s;
typedef __attribute__((ext_vector_type(4))) float v4f;

__device__ __forceinline__ b16 f2b(float f) {
    __hip_bfloat16 h = __float2bfloat16(f);
    return *reinterpret_cast<b16*>(&h);
}
__device__ __forceinline__ float siluf(float x){ return x / (1.f + __expf(-x)); }

// ---- weight transpose+cast: w [tap][ic][128] fp32 -> wt [tap][128][ic] bf16 ----
template<int IC>
__global__ void __launch_bounds__(256) k_wt(const float* __restrict__ w, b16* __restrict__ o, int tot) {
    int i = blockIdx.x*256 + threadIdx.x;
    if (i >= tot) return;
    int ic = i % IC; int oc = (i / IC) & 127; int tap = i / (IC*128);
    o[i] = f2b(w[(tap*IC + ic)*128 + oc]);
}

// ---- A: LN(64)+affine+silu+mask, 2x2x2 masked mean pool; h -> padded buffer ----
__global__ void __launch_bounds__(256) k_ln_down(
    const float* __restrict__ feats, const int* __restrict__ mask,
    const float* __restrict__ gamma, const float* __restrict__ beta,
    b16* __restrict__ h_ds_pad, b16* __restrict__ x_ds, float* __restrict__ cnt_out)
{
    int wave = (blockIdx.x * 256 + threadIdx.x) >> 6;   // cell id, 0..131071
    int lane = threadIdx.x & 63;
    int x = wave & 31, y = (wave >> 5) & 31, z = (wave >> 10) & 31, b = wave >> 15;
    float g = gamma[lane], be = beta[lane];
    float hacc = 0.f, xacc = 0.f, cnt = 0.f;
    #pragma unroll
    for (int i = 0; i < 8; ++i) {
        int zz = 2*z + (i>>2), yy = 2*y + ((i>>1)&1), xx = 2*x + (i&1);
        int vox = ((b*64 + zz)*64 + yy)*64 + xx;
        int m = mask[vox];
        float val = feats[vox*64 + lane];
        float s1 = val, s2 = val*val;
        #pragma unroll
        for (int off = 32; off > 0; off >>= 1) {
            s1 += __shfl_xor(s1, off, 64);
            s2 += __shfl_xor(s2, off, 64);
        }
        float mu = s1 * (1.f/64.f);
        float var = fmaxf(s2 * (1.f/64.f) - mu*mu, 0.f);
        float h = (val - mu) * rsqrtf(var + EPS) * g + be;
        h = siluf(h);
        if (m != 0) { hacc += h; xacc += val; cnt += 1.f; }
    }
    float inv = 1.f / fmaxf(cnt, 1.f);
    long vp = ((long)(b*34 + z+1)*34 + (y+1))*34 + (x+1);
    h_ds_pad[vp*64 + lane] = f2b(hacc * inv);
    x_ds[(long)wave*64 + lane] = f2b(xacc * inv);
    if (lane == 0) cnt_out[wave] = cnt;
}

// ---- MFMA implicit-GEMM conv (27 taps), register-resident fragments ----
// block = 256 thr = 4 waves; tile M=128 (4 y-rows x 32 x), N=128 oc.
// wave w owns y-row y0+w: m-tiles {2w,2w+1}, all 8 n-tiles.
template<int IC, bool IS_CONV1>
__global__ void __launch_bounds__(256) k_conv_mfma(
    const b16* __restrict__ inp,      // padded [b][34][34][34][IC] bf16
    const b16* __restrict__ wt,       // [27][128][IC] bf16
    const float* __restrict__ bias,
    const float* __restrict__ cnt,
    const b16* __restrict__ x_ds,     // conv2 only: [cell][64]
    const b16* __restrict__ wst,      // conv2 only: [128][64]
    const float* __restrict__ b_skip, // conv2 only
    b16* __restrict__ h2out,          // conv1: padded bf16 out [b][34][34][34][128]
    float* __restrict__ out)          // conv2: fp32 out [cell][128]
{
    constexpr int KS = IC/32;
    int bid = blockIdx.x;
    int y0 = (bid & 7) << 2;
    int z  = (bid >> 3) & 31;
    int b  = bid >> 8;
    int lane = threadIdx.x & 63;
    int w = threadIdx.x >> 6;
    int col = lane & 15;
    int quad = lane >> 4;

    v4f acc[2][8];
    #pragma unroll
    for (int t=0;t<2;++t)
        #pragma unroll
        for (int n=0;n<8;++n) acc[t][n] = (v4f){0.f,0.f,0.f,0.f};

    int yrow = y0 + w;
    long vp0 = ((long)(b*34 + z)*34 + yrow)*34 + col;    // tap (0,0,0) already maps to z-1 via pad
    const b16* wbase = wt + col*IC + quad*8;

    for (int tap = 0; tap < 27; ++tap) {
        int kz = tap/9, ky = (tap/3)%3, kx = tap%3;
        const b16* A0 = inp + (vp0 + (long)(kz*34 + ky)*34 + kx)*IC + quad*8;
        const b16* A1 = A0 + 16*IC;
        const b16* W  = wbase + tap*(128*IC);
        #pragma unroll
        for (int s = 0; s < KS; ++s) {
            v8s a0 = *(const v8s*)(A0 + s*32);
            v8s a1 = *(const v8s*)(A1 + s*32);
            #pragma unroll
            for (int n = 0; n < 8; ++n) {
                v8s bb = *(const v8s*)(W + n*16*IC + s*32);
                acc[0][n] = __builtin_amdgcn_mfma_f32_16x16x32_bf16(a0, bb, acc[0][n], 0,0,0);
                acc[1][n] = __builtin_amdgcn_mfma_f32_16x16x32_bf16(a1, bb, acc[1][n], 0,0,0);
            }
        }
    }

    long cellrow = ((long)(b*32+z)*32 + yrow)*32;

    if (!IS_CONV1) {
        // skip GEMM: x_ds[cell][64] @ wst[128][64]^T folded into accumulators
        const b16* X0 = x_ds + (cellrow + col)*64 + quad*8;
        const b16* X1 = X0 + 16*64;
        const b16* WS = wst + col*64 + quad*8;
        #pragma unroll
        for (int s = 0; s < 2; ++s) {
            v8s a0 = *(const v8s*)(X0 + s*32);
            v8s a1 = *(const v8s*)(X1 + s*32);
            #pragma unroll
            for (int n=0;n<8;++n) {
                v8s bb = *(const v8s*)(WS + n*16*64 + s*32);
                acc[0][n] = __builtin_amdgcn_mfma_f32_16x16x32_bf16(a0, bb, acc[0][n], 0,0,0);
                acc[1][n] = __builtin_amdgcn_mfma_f32_16x16x32_bf16(a1, bb, acc[1][n], 0,0,0);
            }
        }
    }

    float bv[8];
    #pragma unroll
    for (int n=0;n<8;++n)
        bv[n] = bias[n*16+col] + (IS_CONV1 ? 0.f : b_skip[n*16+col]);

    long prow = ((long)(b*34 + z+1)*34 + (yrow+1))*34 + 1;

    #pragma unroll
    for (int tl=0; tl<2; ++tl) {
        if (IS_CONV1) {
            // bias + LN(128, no affine) + silu + mask -> padded bf16
            float s1[4], s2[4];
            #pragma unroll
            for (int r=0;r<4;++r){
                float a=0.f, q=0.f;
                #pragma unroll
                for (int n=0;n<8;++n){ float v = acc[tl][n][r] + bv[n]; a+=v; q+=v*v; }
                s1[r]=a; s2[r]=q;
            }
            #pragma unroll
            for (int off=1; off<16; off<<=1){
                #pragma unroll
                for (int r=0;r<4;++r){ s1[r]+=__shfl_xor(s1[r],off); s2[r]+=__shfl_xor(s2[r],off); }
            }
            #pragma unroll
            for (int r=0;r<4;++r){
                int row = quad*4 + r;
                int x = tl*16 + row;
                float c = cnt[cellrow + x];
                float mu = s1[r]*(1.f/128.f);
                float var = fmaxf(s2[r]*(1.f/128.f) - mu*mu, 0.f);
                float rs = rsqrtf(var + EPS);
                bool act = c > 0.f;
                #pragma unroll
                for (int n=0;n<8;++n){
                    float v = acc[tl][n][r] + bv[n];
                    float hv = act ? siluf((v-mu)*rs) : 0.f;
                    h2out[(prow + x)*128 + n*16 + col] = f2b(hv);
                }
            }
        } else {
            #pragma unroll
            for (int r=0;r<4;++r){
                int row = quad*4 + r;
                int x = tl*16 + row;
                float c = cnt[cellrow + x];
                bool act = c > 0.f;
                #pragma unroll
                for (int n=0;n<8;++n){
                    float v = acc[tl][n][r] + bv[n];
                    out[(cellrow + x)*128 + n*16 + col] = act ? v : 0.f;
                }
            }
        }
    }
}

extern "C" void kernel_launch(void* const* d_in, const int* in_sizes, int n_in,
                              void* d_out, int out_size, void* d_ws, size_t ws_size,
                              hipStream_t stream) {
    const float* feats  = (const float*)d_in[0];
    const int*   mask   = (const int*)  d_in[1];
    const float* gamma1 = (const float*)d_in[2];
    const float* beta1  = (const float*)d_in[3];
    const float* w1     = (const float*)d_in[4];
    const float* b1     = (const float*)d_in[5];
    const float* w2     = (const float*)d_in[6];
    const float* b2     = (const float*)d_in[7];
    const float* w_skip = (const float*)d_in[8];
    const float* b_skip = (const float*)d_in[9];
    float* out = (float*)d_out;

    char* ws = (char*)d_ws;
    // offsets (bytes)
    b16*   h_ds_pad = (b16*)(ws);                        // 4*34^3*64*2  = 20,123,648
    b16*   h2_pad   = (b16*)(ws + 20123648);             // 4*34^3*128*2 = 40,247,296
    b16*   x_ds     = (b16*)(ws + 60370944);             // 16,777,216
    float* cnt      = (float*)(ws + 77148160);           // 524,288
    b16*   w1t      = (b16*)(ws + 77672448);             // 442,368
    b16*   w2t      = (b16*)(ws + 78114816);             // 884,736
    b16*   wst      = (b16*)(ws + 78999552);             // 16,384

    // zero halos (interior fully overwritten each launch)
    hipMemsetAsync(h_ds_pad, 0, 20123648, stream);
    hipMemsetAsync(h2_pad,   0, 40247296, stream);

    const int n_w1 = 27*64*128;    // 221184
    const int n_w2 = 27*128*128;   // 442368
    const int n_ws = 64*128;       // 8192
    k_wt<64> <<<(n_w1 + 255)/256, 256, 0, stream>>>(w1, w1t, n_w1);
    k_wt<128><<<(n_w2 + 255)/256, 256, 0, stream>>>(w2, w2t, n_w2);
    k_wt<64> <<<(n_ws + 255)/256, 256, 0, stream>>>(w_skip, wst, n_ws);

    k_ln_down<<<32768, 256, 0, stream>>>(feats, mask, gamma1, beta1, h_ds_pad, x_ds, cnt);

    k_conv_mfma<64,true><<<1024, 256, 0, stream>>>(h_ds_pad, w1t, b1, cnt,
                                                   nullptr, nullptr, nullptr,
                                                   h2_pad, nullptr);
    k_conv_mfma<128,false><<<1024, 256, 0, stream>>>(h2_pad, w2t, b2, cnt,
                                                     x_ds, wst, b_skip,
                                                     nullptr, out);
}

// Round 3
// 700.808 us; speedup vs baseline: 5.7238x; 1.6928x over previous
//
#include <hip/hip_runtime.h>
#include <hip/hip_bf16.h>

#define EPS 1e-6f
typedef unsigned short b16;
typedef __attribute__((ext_vector_type(8))) short v8s;
typedef __attribute__((ext_vector_type(4))) float v4f;

__device__ __forceinline__ b16 f2b(float f) {
    __hip_bfloat16 h = __float2bfloat16(f);
    return *reinterpret_cast<b16*>(&h);
}
__device__ __forceinline__ float siluf(float x){ return x / (1.f + __expf(-x)); }

// ---- skip weight transpose: w [ic][128] fp32 -> [oc][ic] bf16 ----
template<int IC>
__global__ void __launch_bounds__(256) k_wt(const float* __restrict__ w, b16* __restrict__ o, int tot) {
    int i = blockIdx.x*256 + threadIdx.x;
    if (i >= tot) return;
    int ic = i % IC; int oc = (i / IC) & 127; int tap = i / (IC*128);
    o[i] = f2b(w[(tap*IC + ic)*128 + oc]);
}

// ---- conv weight blocked transpose: w [tap][ic][128] fp32 -> [tap][icb][oc][32] bf16 ----
template<int IC>
__global__ void __launch_bounds__(256) k_wtb(const float* __restrict__ w, b16* __restrict__ o, int tot) {
    int i = blockIdx.x*256 + threadIdx.x;
    if (i >= tot) return;
    constexpr int ICB = IC/32;
    int icl = i & 31;
    int oc  = (i >> 5) & 127;
    int r   = i >> 12;              // tap*ICB + icb
    int tap = r / ICB, icb = r % ICB;
    o[i] = f2b(w[(tap*IC + icb*32 + icl)*128 + oc]);
}

// ---- A: LN(64)+affine+silu+mask, 2x2x2 masked mean pool; h -> padded buffer ----
__global__ void __launch_bounds__(256) k_ln_down(
    const float* __restrict__ feats, const int* __restrict__ mask,
    const float* __restrict__ gamma, const float* __restrict__ beta,
    b16* __restrict__ h_ds_pad, b16* __restrict__ x_ds, float* __restrict__ cnt_out)
{
    int wave = (blockIdx.x * 256 + threadIdx.x) >> 6;   // cell id, 0..131071
    int lane = threadIdx.x & 63;
    int x = wave & 31, y = (wave >> 5) & 31, z = (wave >> 10) & 31, b = wave >> 15;
    float g = gamma[lane], be = beta[lane];
    float hacc = 0.f, xacc = 0.f, cnt = 0.f;
    #pragma unroll
    for (int i = 0; i < 8; ++i) {
        int zz = 2*z + (i>>2), yy = 2*y + ((i>>1)&1), xx = 2*x + (i&1);
        int vox = ((b*64 + zz)*64 + yy)*64 + xx;
        int m = mask[vox];
        float val = feats[vox*64 + lane];
        float s1 = val, s2 = val*val;
        #pragma unroll
        for (int off = 32; off > 0; off >>= 1) {
            s1 += __shfl_xor(s1, off, 64);
            s2 += __shfl_xor(s2, off, 64);
        }
        float mu = s1 * (1.f/64.f);
        float var = fmaxf(s2 * (1.f/64.f) - mu*mu, 0.f);
        float h = (val - mu) * rsqrtf(var + EPS) * g + be;
        h = siluf(h);
        if (m != 0) { hacc += h; xacc += val; cnt += 1.f; }
    }
    float inv = 1.f / fmaxf(cnt, 1.f);
    long vp = ((long)(b*34 + z+1)*34 + (y+1))*34 + (x+1);
    h_ds_pad[vp*64 + lane] = f2b(hacc * inv);
    x_ds[(long)wave*64 + lane] = f2b(xacc * inv);
    if (lane == 0) cnt_out[wave] = cnt;
}

// ---- MFMA implicit-GEMM conv: m97-style LDS-staged, BK=32, swizzled ----
// block = 256 thr = 4 waves; C-tile M=128 (4 y-rows x 32 x), N=128 oc.
template<int IC, bool IS_CONV1>
__global__ void __launch_bounds__(256) k_conv_mfma(
    const b16* __restrict__ inp,      // padded [b][34][34][34][IC] bf16
    const b16* __restrict__ wt,       // [tap][icb][128 oc][32 ic] bf16
    const float* __restrict__ bias,
    const float* __restrict__ cnt,
    const b16* __restrict__ x_ds,     // conv2 only: [cell][64]
    const b16* __restrict__ wst,      // conv2 only: [128 oc][64 ic]
    const float* __restrict__ b_skip, // conv2 only
    b16* __restrict__ h2out,          // conv1: padded bf16 out
    float* __restrict__ out)          // conv2: fp32 out [cell][128]
{
    constexpr int ICB = IC/32;
    constexpr int NK = 27*ICB;
    __shared__ b16 lA[4096];   // 8 KB: [v(128)][32ic], 16B-chunk rotated by (x>>1)
    __shared__ b16 lB[4096];   // 8 KB: [oc(128)][32ic], chunk rotated by ((oc&15)>>1)

    int bid = blockIdx.x;
    int y0 = (bid & 7) << 2;
    int z  = (bid >> 3) & 31;
    int b  = bid >> 8;
    int t  = threadIdx.x;
    int lane = t & 63;
    int w = t >> 6;
    int col = lane & 15;
    int quad = lane >> 4;

    // --- staging thread coords (2 x 16B chunks of A, 2 of B per thread) ---
    int av = t >> 1, ac = (t & 1) << 1;          // A: voxel av (0..127), chunks ac, ac+1
    int ayr = av >> 5, ax = av & 31;
    const b16* gA = inp + ((long)((b*34 + z)*34 + (y0 + ayr))*34 + ax)*IC + ac*8;
    int lA0 = av*32 + ((ac     + (ax>>1)) & 3)*8;
    int lA1 = av*32 + ((ac + 1 + (ax>>1)) & 3)*8;
    int ocs = t >> 1, bc = (t & 1) << 1;         // B: oc row ocs, chunks bc, bc+1
    const b16* gB = wt + ocs*32 + bc*8;
    int lB0 = ocs*32 + ((bc     + ((ocs&15)>>1)) & 3)*8;
    int lB1 = ocs*32 + ((bc + 1 + ((ocs&15)>>1)) & 3)*8;

    // --- fragment read offsets ---
    int so   = ((quad + (col>>1)) & 3) * 8;
    int aoff = w*1024 + col*32 + so;
    int boff = col*32 + so;

    v4f acc[2][8];
    #pragma unroll
    for (int tl=0;tl<2;++tl)
        #pragma unroll
        for (int n=0;n<8;++n) acc[tl][n] = (v4f){0.f,0.f,0.f,0.f};

    // prefetch K-step 0 (tap 0 -> off 0)
    v8s ra0 = *(const v8s*)(gA);
    v8s ra1 = *(const v8s*)(gA + 8);
    v8s rb0 = *(const v8s*)(gB);
    v8s rb1 = *(const v8s*)(gB + 8);

    for (int k = 0; k < NK; ++k) {
        *(v8s*)(lA + lA0) = ra0;
        *(v8s*)(lA + lA1) = ra1;
        *(v8s*)(lB + lB0) = rb0;
        *(v8s*)(lB + lB1) = rb1;
        __syncthreads();
        if (k + 1 < NK) {                         // prefetch next step (hidden under MFMA)
            int kn = k + 1;
            int tap = kn / ICB, icb = kn & (ICB-1);
            int kz = tap / 9, rr = tap - kz*9;
            int ky = rr / 3, kx = rr - ky*3;
            long off = ((long)(kz*34 + ky)*34 + kx)*IC + icb*32;
            ra0 = *(const v8s*)(gA + off);
            ra1 = *(const v8s*)(gA + off + 8);
            const b16* gBk = gB + (long)kn*4096;
            rb0 = *(const v8s*)(gBk);
            rb1 = *(const v8s*)(gBk + 8);
        }
        v8s a0 = *(const v8s*)(lA + aoff);
        v8s a1 = *(const v8s*)(lA + aoff + 512);
        #pragma unroll
        for (int n = 0; n < 8; ++n) {
            v8s bb = *(const v8s*)(lB + n*512 + boff);
            acc[0][n] = __builtin_amdgcn_mfma_f32_16x16x32_bf16(a0, bb, acc[0][n], 0,0,0);
            acc[1][n] = __builtin_amdgcn_mfma_f32_16x16x32_bf16(a1, bb, acc[1][n], 0,0,0);
        }
        __syncthreads();
    }

    int yrow = y0 + w;
    long cellrow = ((long)(b*32+z)*32 + yrow)*32;

    if (!IS_CONV1) {
        // skip GEMM: x_ds[cell][64] @ wst[128][64]^T folded into accumulators
        const b16* X0 = x_ds + (cellrow + col)*64 + quad*8;
        const b16* X1 = X0 + 16*64;
        const b16* WS = wst + col*64 + quad*8;
        #pragma unroll
        for (int s = 0; s < 2; ++s) {
            v8s a0 = *(const v8s*)(X0 + s*32);
            v8s a1 = *(const v8s*)(X1 + s*32);
            #pragma unroll
            for (int n=0;n<8;++n) {
                v8s bb = *(const v8s*)(WS + n*16*64 + s*32);
                acc[0][n] = __builtin_amdgcn_mfma_f32_16x16x32_bf16(a0, bb, acc[0][n], 0,0,0);
                acc[1][n] = __builtin_amdgcn_mfma_f32_16x16x32_bf16(a1, bb, acc[1][n], 0,0,0);
            }
        }
    }

    float bv[8];
    #pragma unroll
    for (int n=0;n<8;++n)
        bv[n] = bias[n*16+col] + (IS_CONV1 ? 0.f : b_skip[n*16+col]);

    long prow = ((long)(b*34 + z+1)*34 + (yrow+1))*34 + 1;

    #pragma unroll
    for (int tl=0; tl<2; ++tl) {
        if (IS_CONV1) {
            // bias + LN(128, no affine) + silu + mask -> padded bf16
            float s1[4], s2[4];
            #pragma unroll
            for (int r=0;r<4;++r){
                float a=0.f, q=0.f;
                #pragma unroll
                for (int n=0;n<8;++n){ float v = acc[tl][n][r] + bv[n]; a+=v; q+=v*v; }
                s1[r]=a; s2[r]=q;
            }
            #pragma unroll
            for (int off=1; off<16; off<<=1){
                #pragma unroll
                for (int r=0;r<4;++r){ s1[r]+=__shfl_xor(s1[r],off); s2[r]+=__shfl_xor(s2[r],off); }
            }
            #pragma unroll
            for (int r=0;r<4;++r){
                int row = quad*4 + r;
                int x = tl*16 + row;
                float c = cnt[cellrow + x];
                float mu = s1[r]*(1.f/128.f);
                float var = fmaxf(s2[r]*(1.f/128.f) - mu*mu, 0.f);
                float rs = rsqrtf(var + EPS);
                bool act = c > 0.f;
                #pragma unroll
                for (int n=0;n<8;++n){
                    float v = acc[tl][n][r] + bv[n];
                    float hv = act ? siluf((v-mu)*rs) : 0.f;
                    h2out[(prow + x)*128 + n*16 + col] = f2b(hv);
                }
            }
        } else {
            #pragma unroll
            for (int r=0;r<4;++r){
                int row = quad*4 + r;
                int x = tl*16 + row;
                float c = cnt[cellrow + x];
                bool act = c > 0.f;
                #pragma unroll
                for (int n=0;n<8;++n){
                    float v = acc[tl][n][r] + bv[n];
                    out[(cellrow + x)*128 + n*16 + col] = act ? v : 0.f;
                }
            }
        }
    }
}

extern "C" void kernel_launch(void* const* d_in, const int* in_sizes, int n_in,
                              void* d_out, int out_size, void* d_ws, size_t ws_size,
                              hipStream_t stream) {
    const float* feats  = (const float*)d_in[0];
    const int*   mask   = (const int*)  d_in[1];
    const float* gamma1 = (const float*)d_in[2];
    const float* beta1  = (const float*)d_in[3];
    const float* w1     = (const float*)d_in[4];
    const float* b1     = (const float*)d_in[5];
    const float* w2     = (const float*)d_in[6];
    const float* b2     = (const float*)d_in[7];
    const float* w_skip = (const float*)d_in[8];
    const float* b_skip = (const float*)d_in[9];
    float* out = (float*)d_out;

    char* ws = (char*)d_ws;
    b16*   h_ds_pad = (b16*)(ws);                        // 4*34^3*64*2  = 20,123,648
    b16*   h2_pad   = (b16*)(ws + 20123648);             // 4*34^3*128*2 = 40,247,296
    b16*   x_ds     = (b16*)(ws + 60370944);             // 16,777,216
    float* cnt      = (float*)(ws + 77148160);           // 524,288
    b16*   w1t      = (b16*)(ws + 77672448);             // 442,368
    b16*   w2t      = (b16*)(ws + 78114816);             // 884,736
    b16*   wst      = (b16*)(ws + 78999552);             // 16,384

    // zero halos (interior fully overwritten each launch)
    hipMemsetAsync(h_ds_pad, 0, 20123648, stream);
    hipMemsetAsync(h2_pad,   0, 40247296, stream);

    const int n_w1 = 27*64*128;    // 221184
    const int n_w2 = 27*128*128;   // 442368
    const int n_ws = 64*128;       // 8192
    k_wtb<64> <<<(n_w1 + 255)/256, 256, 0, stream>>>(w1, w1t, n_w1);
    k_wtb<128><<<(n_w2 + 255)/256, 256, 0, stream>>>(w2, w2t, n_w2);
    k_wt<64>  <<<(n_ws + 255)/256, 256, 0, stream>>>(w_skip, wst, n_ws);

    k_ln_down<<<32768, 256, 0, stream>>>(feats, mask, gamma1, beta1, h_ds_pad, x_ds, cnt);

    k_conv_mfma<64,true><<<1024, 256, 0, stream>>>(h_ds_pad, w1t, b1, cnt,
                                                   nullptr, nullptr, nullptr,
                                                   h2_pad, nullptr);
    k_conv_mfma<128,false><<<1024, 256, 0, stream>>>(h2_pad, w2t, b2, cnt,
                                                     x_ds, wst, b_skip,
                                                     nullptr, out);
}